// Round 3
// baseline (196.843 us; speedup 1.0000x reference)
//
#include <hip/hip_runtime.h>

// ---------------------------------------------------------------------------
// JobSchedulerGNN round 3:
//   k_prep   : convert x->bf16, weights->bf16^T, zero deg   (one dispatch)
//   k_count  : degree histogram (atomics)
//   k_scan1  : block-local exclusive scan (+ block totals)
//   k_scan3  : add prefix of block totals (wave-reduced in-kernel)
//   k_fill   : CSR fill via atomic bump
//   k_agg_gemm<HEADS> : per 64-row tile: gather-aggregate into swizzled LDS,
//                       dual MFMA GEMM (agg@Wrel + h@Wroot + b, relu);
//                       layer2 fuses both heads in the epilogue.
// 7 dispatches total; no hipMemsetAsync in the graph.
// ---------------------------------------------------------------------------

#define D 128

typedef unsigned short ushort8 __attribute__((ext_vector_type(8)));
typedef __bf16 bf16x8 __attribute__((ext_vector_type(8)));
typedef float f32x4 __attribute__((ext_vector_type(4)));

__device__ inline unsigned short f2bf(float f) {
  unsigned u = __float_as_uint(f);
  u += 0x7FFFu + ((u >> 16) & 1u);  // RNE
  return (unsigned short)(u >> 16);
}
__device__ inline float bf2f(unsigned short h) {
  return __uint_as_float((unsigned)h << 16);
}

// ---- prep: convert_x | convert_w | zero-deg, selected by blockIdx ----------
__global__ __launch_bounds__(256) void k_prep(
    const float* __restrict__ x, unsigned short* __restrict__ xb, int total8,
    const float* __restrict__ s0, const float* __restrict__ s1,
    const float* __restrict__ s2, const float* __restrict__ s3,
    unsigned short* __restrict__ d0, unsigned short* __restrict__ d1,
    unsigned short* __restrict__ d2, unsigned short* __restrict__ d3,
    int* __restrict__ deg, int n, int xB) {
  int b = blockIdx.x;
  int t = threadIdx.x;
  if (b < xB) {                      // x -> bf16, 8 elems/thread
    int i = b * 256 + t;
    if (i >= total8) return;
    const float4* p = (const float4*)(x + (size_t)i * 8);
    float4 v0 = p[0], v1 = p[1];
    ushort8 o;
    o[0] = f2bf(v0.x); o[1] = f2bf(v0.y); o[2] = f2bf(v0.z); o[3] = f2bf(v0.w);
    o[4] = f2bf(v1.x); o[5] = f2bf(v1.y); o[6] = f2bf(v1.z); o[7] = f2bf(v1.w);
    *(ushort8*)(xb + (size_t)i * 8) = o;
  } else if (b < xB + 256) {         // 4x [128][128] f32 -> bf16 transposed
    int idx = (b - xB) * 256 + t;
    int mat = idx >> 14;
    int rem = idx & 16383;
    int k = rem >> 7, nn = rem & 127;
    const float* s = (mat == 0) ? s0 : (mat == 1) ? s1 : (mat == 2) ? s2 : s3;
    unsigned short* d = (mat == 0) ? d0 : (mat == 1) ? d1 : (mat == 2) ? d2 : d3;
    d[nn * 128 + k] = f2bf(s[k * 128 + nn]);
  } else {                           // zero deg
    int i0 = (b - xB - 256) * 1024 + t * 4;
    #pragma unroll
    for (int i = 0; i < 4; i++)
      if (i0 + i < n) deg[i0 + i] = 0;
  }
}

// ---- CSR build ------------------------------------------------------------
__global__ __launch_bounds__(256) void k_count(const int* __restrict__ dst,
                                               int* __restrict__ deg, int E) {
  int e = blockIdx.x * blockDim.x + threadIdx.x;
  if (e < E) atomicAdd(&deg[dst[e]], 1);
}

__global__ __launch_bounds__(256) void k_scan1(const int* __restrict__ deg,
                                               int* __restrict__ cursor,
                                               int* __restrict__ part, int n) {
  __shared__ int sd[256];
  int t = threadIdx.x;
  int i0 = blockIdx.x * 1024 + t * 4;
  int v0 = (i0 + 0 < n) ? deg[i0 + 0] : 0;
  int v1 = (i0 + 1 < n) ? deg[i0 + 1] : 0;
  int v2 = (i0 + 2 < n) ? deg[i0 + 2] : 0;
  int v3 = (i0 + 3 < n) ? deg[i0 + 3] : 0;
  int s = v0 + v1 + v2 + v3;
  int incl = s;
  sd[t] = incl;
  __syncthreads();
  #pragma unroll
  for (int off = 1; off < 256; off <<= 1) {
    int add = (t >= off) ? sd[t - off] : 0;
    __syncthreads();
    incl += add;
    sd[t] = incl;
    __syncthreads();
  }
  if (t == 255) part[blockIdx.x] = incl;
  int run = incl - s;
  if (i0 + 0 < n) cursor[i0 + 0] = run; run += v0;
  if (i0 + 1 < n) cursor[i0 + 1] = run; run += v1;
  if (i0 + 2 < n) cursor[i0 + 2] = run; run += v2;
  if (i0 + 3 < n) cursor[i0 + 3] = run;
}

// adds prefix-sum of part[0..blockIdx) computed in-kernel (wave reduce).
__global__ __launch_bounds__(256) void k_scan3(int* __restrict__ cursor,
                                               const int* __restrict__ part,
                                               int n) {
  __shared__ int sadd;
  int t = threadIdx.x;
  if (t < 64) {
    int s = 0;
    for (int i = t; i < blockIdx.x; i += 64) s += part[i];
    #pragma unroll
    for (int off = 32; off > 0; off >>= 1) s += __shfl_down(s, off);
    if (t == 0) sadd = s;
  }
  __syncthreads();
  int add = sadd;
  int i0 = blockIdx.x * 1024 + t * 4;
  #pragma unroll
  for (int i = 0; i < 4; i++)
    if (i0 + i < n) cursor[i0 + i] += add;
}

__global__ __launch_bounds__(256) void k_fill(const int* __restrict__ ei,
                                              int* __restrict__ cursor,
                                              int* __restrict__ csr, int E) {
  int e = blockIdx.x * blockDim.x + threadIdx.x;
  if (e < E) {
    int s = ei[e];
    int d = ei[E + e];
    int pos = atomicAdd(&cursor[d], 1);
    csr[pos] = s;
  }
}

// ---- fused aggregate + dual GEMM (+ optional heads) ------------------------
// Tile: 64 rows, 256 threads (4 waves). LDS holds swizzled bf16 agg tile.
// Phase 1: 16 lanes/node gather-sum neighbor rows (bf16, f32 accum) -> LDS.
// Phase 2: wave w rows w*16..+15; acc[nr] over 8 col-tiles; A from LDS
//          (pass rel) then from global rows (pass root); B = WT in global.
// Swizzle both sides: byte ^= ((row&7)<<4)  (rule: both-sides-or-neither).
template <bool HEADS>
__global__ __launch_bounds__(256) void k_agg_gemm(
    const unsigned short* __restrict__ Hprev, const unsigned short* __restrict__ BrelT,
    const unsigned short* __restrict__ BrootT, const int* __restrict__ csr,
    const int* __restrict__ cursor, const int* __restrict__ deg,
    const float* __restrict__ bias, unsigned short* __restrict__ Cout,
    const float* __restrict__ Wa, const float* __restrict__ ba,
    const float* __restrict__ Wo, const float* __restrict__ bo,
    float* __restrict__ out, int n) {
  __shared__ __align__(16) unsigned short sA[64 * D];  // 16 KB
  const int tid = threadIdx.x;
  const int row0 = blockIdx.x * 64;

  // ---- phase 1: aggregate 64 rows into swizzled LDS ----
  {
    const int f = (tid & 15) * 8;
    const int slot = tid >> 4;  // 0..15
    #pragma unroll 1
    for (int nn = 0; nn < 4; nn++) {
      const int rl = slot + nn * 16;
      const int node = row0 + rl;
      float acc[8] = {0.f, 0.f, 0.f, 0.f, 0.f, 0.f, 0.f, 0.f};
      if (node < n) {
        int cnt = deg[node];
        int start = cursor[node] - cnt;
        int j = 0;
        for (; j + 2 <= cnt; j += 2) {
          int a = csr[start + j], b = csr[start + j + 1];
          ushort8 ha = *(const ushort8*)&Hprev[(size_t)a * D + f];
          ushort8 hb = *(const ushort8*)&Hprev[(size_t)b * D + f];
          #pragma unroll
          for (int e = 0; e < 8; e++) acc[e] += bf2f(ha[e]) + bf2f(hb[e]);
        }
        if (j < cnt) {
          int a = csr[start + j];
          ushort8 ha = *(const ushort8*)&Hprev[(size_t)a * D + f];
          #pragma unroll
          for (int e = 0; e < 8; e++) acc[e] += bf2f(ha[e]);
        }
      }
      ushort8 o;
      #pragma unroll
      for (int e = 0; e < 8; e++) o[e] = f2bf(acc[e]);
      int byte = rl * 256 + f * 2;
      byte ^= ((rl & 7) << 4);
      *(ushort8*)((char*)sA + byte) = o;
    }
  }
  __syncthreads();

  // ---- phase 2: dual GEMM ----
  const int w = tid >> 6;
  const int l = tid & 63;
  const int lr = l & 15;
  const int kg = l >> 4;

  f32x4 acc[8];
  f32x4 zf = {0.f, 0.f, 0.f, 0.f};
  #pragma unroll
  for (int nr = 0; nr < 8; nr++) acc[nr] = zf;

  const int rl = w * 16 + lr;  // local A row for this lane
  // pass 0: A = agg tile (LDS), B = BrelT
  #pragma unroll
  for (int k0 = 0; k0 < 128; k0 += 32) {
    const int kb = k0 + kg * 8;
    int byte = rl * 256 + kb * 2;
    byte ^= ((rl & 7) << 4);
    bf16x8 a = *(const bf16x8*)((const char*)sA + byte);
    #pragma unroll
    for (int nr = 0; nr < 8; nr++) {
      uint4 v = *(const uint4*)&BrelT[(size_t)(nr * 16 + lr) * D + kb];
      acc[nr] = __builtin_amdgcn_mfma_f32_16x16x32_bf16(
          a, __builtin_bit_cast(bf16x8, v), acc[nr], 0, 0, 0);
    }
  }
  // pass 1: A = Hprev rows (global), B = BrootT
  const int grow = row0 + rl;
  #pragma unroll
  for (int k0 = 0; k0 < 128; k0 += 32) {
    const int kb = k0 + kg * 8;
    uint4 av = make_uint4(0u, 0u, 0u, 0u);
    if (grow < n) av = *(const uint4*)&Hprev[(size_t)grow * D + kb];
    bf16x8 a = __builtin_bit_cast(bf16x8, av);
    #pragma unroll
    for (int nr = 0; nr < 8; nr++) {
      uint4 v = *(const uint4*)&BrootT[(size_t)(nr * 16 + lr) * D + kb];
      acc[nr] = __builtin_amdgcn_mfma_f32_16x16x32_bf16(
          a, __builtin_bit_cast(bf16x8, v), acc[nr], 0, 0, 0);
    }
  }

  float bcol[8];
  #pragma unroll
  for (int nr = 0; nr < 8; nr++) bcol[nr] = bias[nr * 16 + lr];

  if (!HEADS) {
    // epilogue: relu + bf16 store of h
    #pragma unroll
    for (int r = 0; r < 4; r++) {
      int row = row0 + w * 16 + kg * 4 + r;
      if (row < n) {
        #pragma unroll
        for (int nr = 0; nr < 8; nr++)
          Cout[(size_t)row * D + nr * 16 + lr] =
              f2bf(fmaxf(acc[nr][r] + bcol[nr], 0.f));
      }
    }
  } else {
    // epilogue: heads. lane holds cols {nr*16+lr} of rows kg*4+r.
    float pa0[4] = {0.f, 0.f, 0.f, 0.f};
    float pa1[4] = {0.f, 0.f, 0.f, 0.f};
    float po[4]  = {0.f, 0.f, 0.f, 0.f};
    #pragma unroll
    for (int nr = 0; nr < 8; nr++) {
      const int col = nr * 16 + lr;
      const float wa0 = Wa[col * 2 + 0];
      const float wa1 = Wa[col * 2 + 1];
      const float wo  = Wo[col];
      #pragma unroll
      for (int r = 0; r < 4; r++) {
        float hv = fmaxf(acc[nr][r] + bcol[nr], 0.f);
        pa0[r] += hv * wa0;
        pa1[r] += hv * wa1;
        po[r]  += hv * wo;
      }
    }
    // reduce over the 16-lane lr group (xor 1,2,4,8 stays within group)
    #pragma unroll
    for (int off = 1; off < 16; off <<= 1) {
      #pragma unroll
      for (int r = 0; r < 4; r++) {
        pa0[r] += __shfl_xor(pa0[r], off);
        pa1[r] += __shfl_xor(pa1[r], off);
        po[r]  += __shfl_xor(po[r], off);
      }
    }
    if (lr == 0) {
      const float vba0 = ba[0], vba1 = ba[1], vbo = bo[0];
      #pragma unroll
      for (int r = 0; r < 4; r++) {
        int row = row0 + w * 16 + kg * 4 + r;
        if (row < n) {
          out[(size_t)row * 2 + 0] = pa0[r] + vba0;
          out[(size_t)row * 2 + 1] = pa1[r] + vba1;
          out[(size_t)2 * n + row] = po[r] + vbo;
        }
      }
    }
  }
}

// ---- launch -----------------------------------------------------------------
extern "C" void kernel_launch(void* const* d_in, const int* in_sizes, int n_in,
                              void* d_out, int out_size, void* d_ws, size_t ws_size,
                              hipStream_t stream) {
  const float* x       = (const float*)d_in[0];
  const int*   ei      = (const int*)d_in[1];
  const float* W1_rel  = (const float*)d_in[2];
  const float* b1      = (const float*)d_in[3];
  const float* W1_root = (const float*)d_in[4];
  const float* W2_rel  = (const float*)d_in[5];
  const float* b2      = (const float*)d_in[6];
  const float* W2_root = (const float*)d_in[7];
  const float* Wa      = (const float*)d_in[8];
  const float* ba      = (const float*)d_in[9];
  const float* Wo      = (const float*)d_in[10];
  const float* bo      = (const float*)d_in[11];
  float* out = (float*)d_out;

  const int N = in_sizes[0] / D;
  const int E = in_sizes[1] / 2;

  char* w = (char*)d_ws;
  unsigned short* xb   = (unsigned short*)w; w += (size_t)N * D * 2;
  unsigned short* h1b  = (unsigned short*)w; w += (size_t)N * D * 2;
  unsigned short* WT1r = (unsigned short*)w; w += 128 * 128 * 2;
  unsigned short* WT1x = (unsigned short*)w; w += 128 * 128 * 2;
  unsigned short* WT2r = (unsigned short*)w; w += 128 * 128 * 2;
  unsigned short* WT2x = (unsigned short*)w; w += 128 * 128 * 2;
  int* deg    = (int*)w; w += (size_t)N * 4;
  int* cursor = (int*)w; w += (size_t)N * 4;
  int* csr    = (int*)w; w += (size_t)E * 4;
  int* part   = (int*)w; w += 64 * 4;

  const int nblk = (N + 1023) / 1024;
  const int xB = (N * 16 + 255) / 256;

  k_prep<<<xB + 256 + nblk, 256, 0, stream>>>(
      x, xb, N * 16, W1_rel, W1_root, W2_rel, W2_root,
      WT1r, WT1x, WT2r, WT2x, deg, N, xB);
  k_count<<<(E + 255) / 256, 256, 0, stream>>>(ei + E, deg, E);
  k_scan1<<<nblk, 256, 0, stream>>>(deg, cursor, part, N);
  k_scan3<<<nblk, 256, 0, stream>>>(cursor, part, N);
  k_fill<<<(E + 255) / 256, 256, 0, stream>>>(ei, cursor, csr, E);

  const int gblk = (N + 63) / 64;
  // layer 1: x -> h1
  k_agg_gemm<false><<<gblk, 256, 0, stream>>>(
      xb, WT1r, WT1x, csr, cursor, deg, b1, h1b,
      nullptr, nullptr, nullptr, nullptr, nullptr, N);
  // layer 2 + heads: h1 -> out
  k_agg_gemm<true><<<gblk, 256, 0, stream>>>(
      h1b, WT2r, WT2x, csr, cursor, deg, b2, nullptr,
      Wa, ba, Wo, bo, out, N);
}